// Round 6
// baseline (618.001 us; speedup 1.0000x reference)
//
#include <hip/hip_runtime.h>
#include <math.h>

#define NB 32          // MAX_NODES
#define BATCH 16384
#define STRIDE 36      // row stride in floats: mult of 4 -> 16B-aligned float4 rows

// ws layout (16 B, zeroed by hipMemsetAsync before launch):
// [0]=bce_sum [1]=mask_sum [2]=phys_sum [3]=int completion ticket

__device__ __forceinline__ float groupReduceSum(float v) {
    // sum within each 32-lane half of the wave (xor masks <=16 stay in-half)
    v += __shfl_xor(v, 1, 64);
    v += __shfl_xor(v, 2, 64);
    v += __shfl_xor(v, 4, 64);
    v += __shfl_xor(v, 8, 64);
    v += __shfl_xor(v, 16, 64);
    return v;
}

// One wave (64 threads) per block; 2 matrices per block (lanes 0-31 -> m=0, 32-63 -> m=1).
__global__ __launch_bounds__(64)
void lap_main(const float* __restrict__ predA, const float* __restrict__ targA,
              const float* __restrict__ nmask, float* __restrict__ out,
              float* __restrict__ ws)
{
    __shared__ __align__(16) float A[2][NB][STRIDE];
    __shared__ __align__(16) float V[2][NB];
    __shared__ __align__(16) float W[2][NB];
    __shared__ __align__(16) float NM[2][NB];

    const int t  = threadIdx.x;       // 0..63
    const int m  = t >> 5;            // matrix within block
    const int j  = t & 31;            // row index within matrix
    const int b0 = blockIdx.x * 2;    // first batch index of this block

    // ---- node mask (2 x 32 floats, coalesced) ----
    NM[m][j] = nmask[b0 * NB + t];
    __syncthreads();

    // ---- phase 1: load pred/target coalesced, BCE partials, stage pred into LDS ----
    float accB = 0.f, accM = 0.f;
    const float4* p4 = (const float4*)predA + (size_t)blockIdx.x * 512;
    const float4* t4 = (const float4*)targA + (size_t)blockIdx.x * 512;
    #pragma unroll
    for (int q = 0; q < 8; ++q) {
        const int fi = t + q * 64;         // float4 index within block's 2048 floats
        float4 p  = p4[fi];
        float4 tg = t4[fi];
        const int e  = fi << 2;            // element index 0..2047
        const int mm = e >> 10;            // which matrix
        const int r  = (e >> 5) & 31;      // row
        const int c  = e & 31;             // col (multiple of 4)
        *(float4*)&A[mm][r][c] = p;
        const float  mr = NM[mm][r];
        const float4 mc = *(const float4*)&NM[mm][c];
        const float bx = -(tg.x * __logf(p.x) + (1.f - tg.x) * __logf(1.f - p.x));
        const float by = -(tg.y * __logf(p.y) + (1.f - tg.y) * __logf(1.f - p.y));
        const float bz = -(tg.z * __logf(p.z) + (1.f - tg.z) * __logf(1.f - p.z));
        const float bw = -(tg.w * __logf(p.w) + (1.f - tg.w) * __logf(1.f - p.w));
        accB += mr * (mc.x * bx + mc.y * by + mc.z * bz + mc.w * bw);
        accM += mr * (mc.x + mc.y + mc.z + mc.w);
    }
    // full-wave reduce; one atomic pair per block
    accB = groupReduceSum(accB); accB += __shfl_xor(accB, 32, 64);
    accM = groupReduceSum(accM); accM += __shfl_xor(accM, 32, 64);
    if (t == 0) { atomicAdd(ws + 0, accB); atomicAdd(ws + 1, accM); }
    __syncthreads();

    // ---- phase 2: M = (L + L^T)/2, L = diag(rowsum+jitter) - pred  (JAX symmetrizes) ----
    // Bitwise-symmetric: lane j writes -0.5*(A[j][i]+A[i][j]); fp add commutes.
    {
        float a[NB];
        #pragma unroll
        for (int i4 = 0; i4 < 8; ++i4) {
            float4 r = *(const float4*)&A[m][j][i4 * 4];
            a[4*i4+0]=r.x; a[4*i4+1]=r.y; a[4*i4+2]=r.z; a[4*i4+3]=r.w;
        }
        float dsum = 0.f;
        #pragma unroll
        for (int i = 0; i < NB; ++i) dsum += a[i];
        float col[NB];                                 // column j (conflict-free: bank 4i+j)
        #pragma unroll
        for (int i = 0; i < NB; ++i) col[i] = A[m][i][j];
        const float pdiag = A[m][j][j];
        const float jitter = 1e-5f + (9e-5f / 31.f) * (float)j;
        const float dval = dsum + jitter - pdiag;
        #pragma unroll
        for (int i = 0; i < NB; ++i) {
            const float s = -0.5f * (a[i] + col[i]);
            a[i] = (i == j) ? dval : s;
        }
        __syncthreads();                               // all reads done before any write
        #pragma unroll
        for (int i4 = 0; i4 < 8; ++i4)
            *(float4*)&A[m][j][i4 * 4] = make_float4(a[4*i4+0], a[4*i4+1], a[4*i4+2], a[4*i4+3]);
        __syncthreads();
    }

    // ---- phase 3: Householder tridiagonalization (R3-verified dataflow) ----
    // H = I - beta*v*v^T, beta = 2/(v^T v) = 1/denom
    // p = beta*A*v ; K = v.p ; w = p - 0.5*beta*K*v ; A -= v w^T + w v^T
    for (int k = 0; k < NB - 2; ++k) {
        const float xj = (j > k) ? A[m][j][k] : 0.f;
        const float sg = groupReduceSum(xj * xj);
        const float x1 = __shfl(xj, k + 1, 32);
        const float al = (x1 >= 0.f) ? -sqrtf(sg) : sqrtf(sg);
        const float denom = sg - al * x1;                 // = sg + |x1|*sqrt(sg) >= 0
        const float beta = (denom > 1e-30f) ? 1.f / denom : 0.f;
        const float vj = xj - ((j == k + 1) ? al : 0.f);  // zero-padded for j<=k
        V[m][j] = vj;
        __syncthreads();
        const int i40 = k >> 2;                            // cover i >= k
        float pj = 0.f;
        for (int i4 = i40; i4 < 8; ++i4) {
            float4 a  = *(const float4*)&A[m][j][i4 * 4];
            float4 vv = *(const float4*)&V[m][i4 * 4];
            pj += a.x * vv.x + a.y * vv.y + a.z * vv.z + a.w * vv.w;
        }
        pj *= beta;                                        // p = beta*A*v (all rows)
        const float K = groupReduceSum(vj * pj);           // v.p
        const float wj = pj - 0.5f * beta * K * vj;
        W[m][j] = wj;
        __syncthreads();
        if (j >= k) {                                      // rows <k provably unchanged
            for (int i4 = i40; i4 < 8; ++i4) {
                float4 a  = *(float4*)&A[m][j][i4 * 4];
                float4 vv = *(const float4*)&V[m][i4 * 4];
                float4 ww = *(const float4*)&W[m][i4 * 4];
                a.x -= vj * ww.x + wj * vv.x;
                a.y -= vj * ww.y + wj * vv.y;
                a.z -= vj * ww.z + wj * vv.z;
                a.w -= vj * ww.w + wj * vv.w;
                *(float4*)&A[m][j][i4 * 4] = a;
            }
        }
        __syncthreads();
    }

    // ---- phase 4: Sturm multisection for lambda_2 (32 sigmas/round, 4 rounds) ----
    float d[NB], e[NB];
    #pragma unroll
    for (int i = 0; i < NB; ++i) d[i] = A[m][i][i];
    #pragma unroll
    for (int i = 0; i < NB - 1; ++i) e[i] = A[m][i + 1][i];
    e[NB - 1] = 0.f;

    float lo = 1e30f, hi = -1e30f;
    #pragma unroll
    for (int i = 0; i < NB; ++i) {
        const float r = ((i > 0) ? fabsf(e[i - 1]) : 0.f) + ((i < NB - 1) ? fabsf(e[i]) : 0.f);
        lo = fminf(lo, d[i] - r);
        hi = fmaxf(hi, d[i] + r);
    }

    for (int round = 0; round < 4; ++round) {
        const float step = (hi - lo) * (1.f / 33.f);
        const float sig = lo + step * (float)(j + 1);
        float q = d[0] - sig;
        int cnt = (q < 0.f);
        #pragma unroll
        for (int i = 1; i < NB; ++i) {
            if (fabsf(q) < 1e-20f) q = (q < 0.f) ? -1e-20f : 1e-20f;
            q = (d[i] - sig) - (e[i - 1] * e[i - 1]) / q;
            cnt += (q < 0.f);
        }
        const unsigned long long bal = __ballot(cnt >= 2);
        const unsigned int bits = (unsigned int)(bal >> (m * 32));
        const int jstar = (bits == 0u) ? 32 : __builtin_ctz(bits);
        const float nlo = lo + step * (float)jstar;
        const float nhi = lo + step * (float)(jstar + 1);
        lo = nlo; hi = nhi;
    }
    const float lam2 = 0.5f * (lo + hi);

    if (j == 0) out[2 + b0 + m] = lam2;
    const float ph = fmaxf(0.1f - lam2, 0.f);
    const float ph0 = __shfl(ph, 0, 64);
    const float ph1 = __shfl(ph, 32, 64);
    if (t == 0) atomicAdd(ws + 2, ph0 + ph1);

    // ---- finalize: last block computes the two scalar losses ----
    if (t == 0) {
        __threadfence();
        int* wsi = (int*)ws;
        const int ticket = __hip_atomic_fetch_add(&wsi[3], 1, __ATOMIC_ACQ_REL,
                                                  __HIP_MEMORY_SCOPE_AGENT);
        if (ticket == (int)gridDim.x - 1) {
            const float sb = __hip_atomic_load(&ws[0], __ATOMIC_RELAXED, __HIP_MEMORY_SCOPE_AGENT);
            const float sm = __hip_atomic_load(&ws[1], __ATOMIC_RELAXED, __HIP_MEMORY_SCOPE_AGENT);
            const float sp = __hip_atomic_load(&ws[2], __ATOMIC_RELAXED, __HIP_MEMORY_SCOPE_AGENT);
            out[0] = sb / fmaxf(sm, 1.f);
            out[1] = sp * (1.f / (float)BATCH);
        }
    }
}

extern "C" void kernel_launch(void* const* d_in, const int* in_sizes, int n_in,
                              void* d_out, int out_size, void* d_ws, size_t ws_size,
                              hipStream_t stream) {
    const float* pred = (const float*)d_in[0];
    const float* targ = (const float*)d_in[1];
    const float* nm   = (const float*)d_in[2];
    float* out = (float*)d_out;
    float* ws  = (float*)d_ws;

    (void)hipMemsetAsync(d_ws, 0, 16, stream);   // stream op: graph-capture safe
    hipLaunchKernelGGL(lap_main, dim3(BATCH / 2), dim3(64), 0, stream,
                       pred, targ, nm, out, ws);
}

// Round 7
// 470.077 us; speedup vs baseline: 1.3147x; 1.3147x over previous
//
#include <hip/hip_runtime.h>
#include <math.h>

#define NB 32          // MAX_NODES
#define BATCH 16384
#define STRIDE 36      // A-staging row stride: 16B-aligned, bank-spread

// ws layout (16 B, zeroed by hipMemsetAsync): [0]=bce_sum [1]=mask_sum [2]=phys_sum [3]=unused

__device__ __forceinline__ float groupReduceSum(float v) {
    v += __shfl_xor(v, 1, 64);
    v += __shfl_xor(v, 2, 64);
    v += __shfl_xor(v, 4, 64);
    v += __shfl_xor(v, 8, 64);
    v += __shfl_xor(v, 16, 64);
    return v;
}

// One wave (64 threads) per block; 2 matrices per block (lanes 0-31 -> m=0, 32-63 -> m=1).
// 1-wave blocks make __syncthreads() ~free (single-wave s_barrier) — phase 3 relies on this.
__global__ __launch_bounds__(64)
void lap_main(const float* __restrict__ predA, const float* __restrict__ targA,
              const float* __restrict__ nmask, float* __restrict__ out,
              float* __restrict__ ws)
{
    // S: A staging (rows j*STRIDE) during phases 1-2; after that re-used as
    // X (cols 0..31), P (32..63), D (64..95), E (96..127) transpose buffers.
    __shared__ __align__(16) float S[2][NB * STRIDE];
    __shared__ __align__(16) float NM[2][NB];

    const int t  = threadIdx.x;       // 0..63
    const int m  = t >> 5;            // matrix within block
    const int j  = t & 31;            // row index within matrix
    const int b0 = blockIdx.x * 2;    // first batch index of this block

    NM[m][j] = nmask[b0 * NB + t];
    __syncthreads();

    // ---- phase 1 (R3-verified): coalesced loads, BCE partials, stage pred into LDS ----
    float accB = 0.f, accM = 0.f;
    const float4* p4 = (const float4*)predA + (size_t)blockIdx.x * 512;
    const float4* t4 = (const float4*)targA + (size_t)blockIdx.x * 512;
    #pragma unroll
    for (int q = 0; q < 8; ++q) {
        const int fi = t + q * 64;
        float4 p  = p4[fi];
        float4 tg = t4[fi];
        const int e  = fi << 2;
        const int mm = e >> 10;
        const int r  = (e >> 5) & 31;
        const int c  = e & 31;
        *(float4*)&S[mm][r * STRIDE + c] = p;
        const float  mr = NM[mm][r];
        const float4 mc = *(const float4*)&NM[mm][c];
        const float bx = -(tg.x * __logf(p.x) + (1.f - tg.x) * __logf(1.f - p.x));
        const float by = -(tg.y * __logf(p.y) + (1.f - tg.y) * __logf(1.f - p.y));
        const float bz = -(tg.z * __logf(p.z) + (1.f - tg.z) * __logf(1.f - p.z));
        const float bw = -(tg.w * __logf(p.w) + (1.f - tg.w) * __logf(1.f - p.w));
        accB += mr * (mc.x * bx + mc.y * by + mc.z * bz + mc.w * bw);
        accM += mr * (mc.x + mc.y + mc.z + mc.w);
    }
    accB = groupReduceSum(accB); accB += __shfl_xor(accB, 32, 64);
    accM = groupReduceSum(accM); accM += __shfl_xor(accM, 32, 64);
    if (t == 0) { atomicAdd(ws + 0, accB); atomicAdd(ws + 1, accM); }  // relaxed, no fence
    __syncthreads();

    // ---- phase 2 (R6-verified): M = (L+L^T)/2 built into registers a[32] ----
    float a[NB];
    #pragma unroll
    for (int i4 = 0; i4 < 8; ++i4) {
        float4 r = *(const float4*)&S[m][j * STRIDE + i4 * 4];
        a[4*i4+0]=r.x; a[4*i4+1]=r.y; a[4*i4+2]=r.z; a[4*i4+3]=r.w;
    }
    float dsum = 0.f;
    #pragma unroll
    for (int i = 0; i < NB; ++i) dsum += a[i];
    {
        float col[NB];                              // column j: bank (4i+j)%32, conflict-free
        #pragma unroll
        for (int i = 0; i < NB; ++i) col[i] = S[m][i * STRIDE + j];
        const float jitter = 1e-5f + (9e-5f / 31.f) * (float)j;
        const float dval = dsum + jitter - a[j];    // a[j] == pred[j][j]
        #pragma unroll
        for (int i = 0; i < NB; ++i) {
            const float s = -0.5f * (a[i] + col[i]);
            a[i] = (i == j) ? dval : s;
        }
    }
    __syncthreads();                                // all A-staging reads done; S reusable

    float* X = &S[m][0];
    float* P = &S[m][NB];

    // ---- phase 3: register-resident Householder, fully unrolled (k compile-time) ----
    // Dataflow identical to R3: v sourced from COLUMN k (each lane contributes a[k]),
    // sg/x1/al/beta/K computed locally from the shared X/P vectors (bitwise-uniform
    // across lanes). No shuffle reductions, no row/col symmetry assumption.
    float dcap = 0.f, ecap = 0.f;
    #pragma unroll
    for (int k = 0; k < NB - 2; ++k) {
        X[j] = a[k];                                // ds_write_b32, bank j: conflict-free
        __syncthreads();
        float xv[NB];
        #pragma unroll
        for (int i4 = 0; i4 < 8; ++i4) {            // broadcast b128 reads: conflict-free
            if (i4 >= ((k + 1) >> 2)) {
                float4 r = *(const float4*)&X[i4 * 4];
                xv[4*i4+0]=r.x; xv[4*i4+1]=r.y; xv[4*i4+2]=r.z; xv[4*i4+3]=r.w;
            }
        }
        float sg = 0.f;
        #pragma unroll
        for (int i = 0; i < NB; ++i) if (i > k) sg += xv[i] * xv[i];
        const float x1 = xv[k + 1];
        const float al = (x1 >= 0.f) ? -sqrtf(sg) : sqrtf(sg);
        const float denom = sg - al * x1;
        const float beta = (denom > 1e-30f) ? 1.f / denom : 0.f;
        const float vj = (j > k) ? (a[k] - ((j == k + 1) ? al : 0.f)) : 0.f;
        float dot = 0.f;                            // a_row . v  (v_i = xv[i] - al*delta_{k+1})
        #pragma unroll
        for (int i = 0; i < NB; ++i) if (i > k) dot += a[i] * xv[i];
        const float pj = beta * (dot - al * a[k + 1]);
        P[j] = pj;
        __syncthreads();
        float pv[NB];
        #pragma unroll
        for (int i4 = 0; i4 < 8; ++i4) {
            if (i4 >= (k >> 2)) {
                float4 r = *(const float4*)&P[i4 * 4];
                pv[4*i4+0]=r.x; pv[4*i4+1]=r.y; pv[4*i4+2]=r.z; pv[4*i4+3]=r.w;
            }
        }
        float K = 0.f;                              // v . p, local
        #pragma unroll
        for (int i = 0; i < NB; ++i) if (i > k) {
            const float vi = xv[i] - ((i == k + 1) ? al : 0.f);
            K += vi * pv[i];
        }
        const float c  = 0.5f * beta * K;
        const float wj = pj - c * vj;
        if (j >= k) {                               // rows < k frozen (finalized)
            a[k] -= vj * pv[k];                     // i=k: v_k=0, w_k=p_k (annihilation)
            #pragma unroll
            for (int i = 0; i < NB; ++i) if (i > k) {
                const float vi = xv[i] - ((i == k + 1) ? al : 0.f);
                const float wi = pv[i] - c * vi;
                a[i] -= vj * wi + wj * vi;
            }
        }
        if (j == k)     dcap = a[k];                // d_k final after step k
        if (j == k + 1) ecap = a[k];                // e_k = A[k+1][k] final after step k
    }
    if (j == NB - 2) dcap = a[NB - 2];              // trailing 2x2 block
    if (j == NB - 1) { dcap = a[NB - 1]; ecap = a[NB - 2]; }

    // ---- transpose d/e to all lanes via LDS ----
    float* D = &S[m][2 * NB];
    float* E = &S[m][3 * NB];
    D[j] = dcap;
    if (j > 0) E[j - 1] = ecap;
    else       E[NB - 1] = 0.f;
    __syncthreads();
    float d[NB], e[NB];
    #pragma unroll
    for (int i4 = 0; i4 < 8; ++i4) {
        float4 rd = *(const float4*)&D[i4 * 4];
        float4 re = *(const float4*)&E[i4 * 4];
        d[4*i4+0]=rd.x; d[4*i4+1]=rd.y; d[4*i4+2]=rd.z; d[4*i4+3]=rd.w;
        e[4*i4+0]=re.x; e[4*i4+1]=re.y; e[4*i4+2]=re.z; e[4*i4+3]=re.w;
    }

    // ---- phase 4: Sturm multisection for lambda_2 (32 sigmas/round, 3 rounds) ----
    float lo = 1e30f, hi = -1e30f;
    #pragma unroll
    for (int i = 0; i < NB; ++i) {
        const float r = ((i > 0) ? fabsf(e[i - 1]) : 0.f) + ((i < NB - 1) ? fabsf(e[i]) : 0.f);
        lo = fminf(lo, d[i] - r);
        hi = fmaxf(hi, d[i] + r);
    }
    for (int round = 0; round < 3; ++round) {
        const float step = (hi - lo) * (1.f / 33.f);
        const float sig = lo + step * (float)(j + 1);
        float q = d[0] - sig;
        int cnt = (q < 0.f);
        #pragma unroll
        for (int i = 1; i < NB; ++i) {
            if (fabsf(q) < 1e-20f) q = (q < 0.f) ? -1e-20f : 1e-20f;
            q = (d[i] - sig) - (e[i - 1] * e[i - 1]) / q;
            cnt += (q < 0.f);
        }
        const unsigned long long bal = __ballot(cnt >= 2);
        const unsigned int bits = (unsigned int)(bal >> (m * 32));
        const int jstar = (bits == 0u) ? 32 : __builtin_ctz(bits);
        const float nlo = lo + step * (float)jstar;
        const float nhi = lo + step * (float)(jstar + 1);
        lo = nlo; hi = nhi;
    }
    const float lam2 = 0.5f * (lo + hi);

    if (j == 0) out[2 + b0 + m] = lam2;
    const float ph = fmaxf(0.1f - lam2, 0.f);
    const float ph0 = __shfl(ph, 0, 64);
    const float ph1 = __shfl(ph, 32, 64);
    if (t == 0) atomicAdd(ws + 2, ph0 + ph1);       // relaxed; NO fence, NO ticket (R6 lesson)
}

__global__ __launch_bounds__(64)
void lap_final(float* __restrict__ out, const float* __restrict__ ws) {
    if (threadIdx.x == 0) {
        out[0] = ws[0] / fmaxf(ws[1], 1.f);
        out[1] = ws[2] * (1.f / (float)BATCH);
    }
}

extern "C" void kernel_launch(void* const* d_in, const int* in_sizes, int n_in,
                              void* d_out, int out_size, void* d_ws, size_t ws_size,
                              hipStream_t stream) {
    const float* pred = (const float*)d_in[0];
    const float* targ = (const float*)d_in[1];
    const float* nm   = (const float*)d_in[2];
    float* out = (float*)d_out;
    float* ws  = (float*)d_ws;

    (void)hipMemsetAsync(d_ws, 0, 16, stream);
    hipLaunchKernelGGL(lap_main, dim3(BATCH / 2), dim3(64), 0, stream,
                       pred, targ, nm, out, ws);
    hipLaunchKernelGGL(lap_final, dim3(1), dim3(64), 0, stream, out, ws);
}